// Round 12
// baseline (193.212 us; speedup 1.0000x reference)
//
#include <hip/hip_runtime.h>

#define K_BINS 1025
#define T_LEN  2000
#define NF     128
#define TQ     500    // t per block (2000 = 4*500, no tail)
#define ROWQ   500    // float4 per full k-row
#define WSTEPS 12     // max support span: bw*(s0+s1) ~= 11.36 bins -> <= 12 rows

__device__ __forceinline__ float softplusf(float x) {
    // matches jax.nn.softplus = max(x,0) + log1p(exp(-|x|))
    return fmaxf(x, 0.0f) + log1pf(expf(-fabsf(x)));
}

// out[b2][t][4*bp + w] = sum_k w_f(k) * spec[bp][k][t],  f = b2 + 32*w
// Block = (bp-quad q, b2-quad B, t-quarter th). 1024 thr = 16 waves (w,p).
// Wave (w,p): filters f = 4B+32w+i (i=0..3) for bp = 4q+p, t-chunk of 500.
// Fixed 12-step fully-unrolled branch-free walk per filter; address clamps
// to row 1024, weight masked 0 for k >= K_BINS.
// R12 vs R11: __launch_bounds__(1024,4) -> 128 VGPR (R11's 64-VGPR cap
// spilled the hoisted loads to scratch: 207 MB of HBM writes). Epilogue LDS
// is column-major [16][516]: float4 ds_write_b128 (conflict-free) + scalar
// reads at 2-way (free) instead of 8-way scalar writes (1M conflict cycles).
__global__ __launch_bounds__(1024, 4) void fb_fused(
        const float* __restrict__ spec,
        const float* __restrict__ cf,
        const float* __restrict__ bwv,
        const float* __restrict__ fs,
        float*       __restrict__ out) {
    const int q    = blockIdx.x;   // bp-quad 0..7 (id%8 -> XCD q)
    const int B    = blockIdx.y;   // b2-quad 0..7
    const int th   = blockIdx.z;   // t-quarter 0..3
    const int tid  = threadIdx.x;
    const int lane = tid & 63;
    const int wid  = tid >> 6;     // 0..15
    const int w    = wid >> 2;     // filter band 0..3
    const int p    = wid & 3;      // bp-local 0..3
    const int bp   = 4 * q + p;
    const int t0   = TQ * th;
    const bool ok1 = lane < (TQ / 4 - 64);       // second float4 live (lane<61)
    const int  li1 = min(64 + lane, TQ / 4 - 1); // clamped: in-bounds, dead lanes
                                                 // discarded in epilogue

    const float4* base4 =
        (const float4*)(spec + (size_t)bp * (K_BINS * (size_t)T_LEN) + t0);

    float4 acc[4][2];              // [filter i][t-half]
#pragma unroll
    for (int i = 0; i < 4; ++i) {
        acc[i][0] = make_float4(0.f, 0.f, 0.f, 0.f);
        acc[i][1] = make_float4(0.f, 0.f, 0.f, 0.f);
    }

#pragma unroll
    for (int i = 0; i < 4; ++i) {
        const int f = 4 * B + 32 * w + i;
        float c  = cf[f];
        float bw = softplusf(bwv[f]) + 0.001f;
        float s0 = softplusf(fs[2 * f])     + 0.1f;
        float s1 = softplusf(fs[2 * f + 1]) + 0.1f;
        float left  = c - bw * s0;
        float right = c + bw * s1;
        float ic = 1.0f / (c - left + 1e-8f);
        float ir = 1.0f / (right - c + 1e-8f);
        float mA = -left * ic;              // rise = fk*ic + mA
        float Bf = fmaf(c, ir, 1.0f);       // fall = -fk*ir + Bf
        const int klo = max(0, (int)ceilf(left));

#pragma unroll
        for (int m = 0; m < WSTEPS; ++m) {
            const int k  = klo + m;
            const int kc = min(k, K_BINS - 1);          // safe address
            const float4* rp = base4 + (size_t)kc * ROWQ;
            float4 v0 = rp[lane];
            float4 v1 = rp[li1];
            float fk  = (float)k;                       // UNclamped for weight
            float wg  = fmaxf(0.0f,
                              fminf(fmaf(fk, ic, mA), fmaf(-fk, ir, Bf)));
            wg = (k < K_BINS) ? wg : 0.0f;              // top-boundary mask
            acc[i][0].x = fmaf(wg, v0.x, acc[i][0].x);
            acc[i][0].y = fmaf(wg, v0.y, acc[i][0].y);
            acc[i][0].z = fmaf(wg, v0.z, acc[i][0].z);
            acc[i][0].w = fmaf(wg, v0.w, acc[i][0].w);
            acc[i][1].x = fmaf(wg, v1.x, acc[i][1].x);
            acc[i][1].y = fmaf(wg, v1.y, acc[i][1].y);
            acc[i][1].z = fmaf(wg, v1.z, acc[i][1].z);
            acc[i][1].w = fmaf(wg, v1.w, acc[i][1].w);
        }
    }

    // Epilogue: per filter i, col-major LDS transpose, full 64 B line stores.
    __shared__ float tile2[16][516];   // [f2-16q][t-local], 516 -> 2-way reads
#pragma unroll
    for (int i = 0; i < 4; ++i) {
        __syncthreads();               // protect tile reuse
        {
            const int col = 4 * p + w; // f2 - 16q
            *reinterpret_cast<float4*>(&tile2[col][4 * lane]) = acc[i][0];
            if (ok1)
                *reinterpret_cast<float4*>(&tile2[col][256 + 4 * lane]) = acc[i][1];
        }
        __syncthreads();
        const int b2 = 4 * B + i;
        const int c4 = tid & 3;
#pragma unroll
        for (int rr = 0; rr < 2; ++rr) {
            int tl = 256 * rr + (tid >> 2);
            if (tl < TQ) {
                float4 v = make_float4(tile2[4 * c4 + 0][tl], tile2[4 * c4 + 1][tl],
                                       tile2[4 * c4 + 2][tl], tile2[4 * c4 + 3][tl]);
                *reinterpret_cast<float4*>(
                    out + ((size_t)b2 * T_LEN + t0 + tl) * NF + 16 * q + 4 * c4) = v;
            }
        }
    }
}

extern "C" void kernel_launch(void* const* d_in, const int* in_sizes, int n_in,
                              void* d_out, int out_size, void* d_ws, size_t ws_size,
                              hipStream_t stream) {
    const float* spec = (const float*)d_in[0];   // (32, 1025, 2000) f32
    const float* cf   = (const float*)d_in[1];   // (128,)
    const float* bwv  = (const float*)d_in[2];   // (128,)
    const float* fs   = (const float*)d_in[3];   // (128, 2)
    float* out = (float*)d_out;                  // (32, 2000, 128) f32

    fb_fused<<<dim3(8, 8, 4), 1024, 0, stream>>>(spec, cf, bwv, fs, out);
}

// Round 13
// 82.027 us; speedup vs baseline: 2.3555x; 2.3555x over previous
//
#include <hip/hip_runtime.h>

#define K_BINS 1025
#define T_LEN  2000
#define NF     128
#define TQ     500    // t per block (2000 = 4*500, no tail)
#define ROWQ   500    // float4 per full k-row
#define SLOTF4 128    // float4 per LDS ring slot (125 used)

__device__ __forceinline__ float softplusf(float x) {
    // matches jax.nn.softplus = max(x,0) + log1p(exp(-|x|))
    return fmaxf(x, 0.0f) + log1pf(expf(-fabsf(x)));
}

// async global -> LDS, 16 B per lane. LDS dest is wave-uniform base (+lane*16
// by HW); global src is per-lane.
__device__ __forceinline__ void load_lds16(const float4* g, float4* l) {
    __builtin_amdgcn_global_load_lds(
        (const __attribute__((address_space(1))) void*)g,
        (__attribute__((address_space(3))) void*)l, 16, 0, 0);
}

__device__ __forceinline__ int sel8(int r, int a0, int a1, int a2, int a3,
                                    int a4, int a5, int a6, int a7) {
    int v = a0;
    v = (r == 1) ? a1 : v; v = (r == 2) ? a2 : v; v = (r == 3) ? a3 : v;
    v = (r == 4) ? a4 : v; v = (r == 5) ? a5 : v; v = (r == 6) ? a6 : v;
    v = (r == 7) ? a7 : v;
    return v;
}

// out[b2][t][4*bp + w] = sum_k w_f(k) * spec[bp][k][t],  f = b2 + 32*w
// Block = (bp-quad q, b2-quad B, t-quarter th). 512 thr = 8 waves (jj,p).
// Wave (jj,p): bp = 4q+p, band pair {jj, 3-jj} of quad B (8 filters) --
// pairing balances rows/wave (R7's 17..45 spread -> ~49..59). One
// concatenated merged-run walk; triangle weight self-masks out-of-band rows.
// Rows are staged into a per-wave 4-slot LDS ring via global_load_lds with
// explicit counted s_waitcnt vmcnt(6/4/2/0): pipeline depth lives in the HW
// vmem queue, not registers (R11/R12 spilled; R6-R9 serialized at 1 row in
// flight). 96 KB LDS forces 1 block/CU -> compiler VGPR budget 256, no spill.
// Epilogue: col-major LDS tile [16][516], float4 ds_write, full-line stores.
__global__ __launch_bounds__(512) void fb_fused(
        const float* __restrict__ spec,
        const float* __restrict__ cf,
        const float* __restrict__ bwv,
        const float* __restrict__ fs,
        float*       __restrict__ out) {
    __shared__ float4 smem4[6144];     // 96 KB: 8 waves x 4 slots x 2 KB + pad
    const int q    = blockIdx.x;       // bp-quad 0..7 (id%8 -> XCD q)
    const int B    = blockIdx.y;       // b2-quad 0..7
    const int th   = blockIdx.z;       // t-quarter 0..3
    const int tid  = threadIdx.x;
    const int lane = tid & 63;
    const int wid  = tid >> 6;         // 0..7
    const int jj   = wid >> 2;         // band-pair 0..1 -> bands {jj, 3-jj}
    const int p    = wid & 3;          // bp-local 0..3
    const int bp   = 4 * q + p;
    const int t0   = TQ * th;
    const bool ok1 = lane < (TQ / 4 - 64);        // second float4 live (lane<61)
    const int  li1 = min(64 + lane, TQ / 4 - 1);  // clamped global idx

    const float4* base4 =
        (const float4*)(spec + (size_t)bp * (K_BINS * (size_t)T_LEN) + t0);
    float4* slab = smem4 + wid * (4 * SLOTF4);

    // ---- params for 8 filters: tasks s=0,1 -> bands jj, 3-jj ----
    float ic[2][4], mir[2][4], mA[2][4], Bf[2][4];   // static-indexed only
    int   kloA[8], khiA[8];                          // static-indexed only
#pragma unroll
    for (int s = 0; s < 2; ++s) {
        const int band = s ? (3 - jj) : jj;
#pragma unroll
        for (int i = 0; i < 4; ++i) {
            const int f = 4 * B + 32 * band + i;
            float c  = cf[f];
            float bw = softplusf(bwv[f]) + 0.001f;
            float s0 = softplusf(fs[2 * f])     + 0.1f;
            float s1 = softplusf(fs[2 * f + 1]) + 0.1f;
            float left  = c - bw * s0;
            float right = c + bw * s1;
            float icv = 1.0f / (c - left + 1e-8f);
            float irv = 1.0f / (right - c + 1e-8f);
            ic[s][i]  = icv;
            mir[s][i] = -irv;
            mA[s][i]  = -left * icv;           // rise = fk*ic + mA
            Bf[s][i]  = fmaf(c, irv, 1.0f);    // fall = fk*mir + Bf
            kloA[4 * s + i] = max(0, (int)ceilf(left));
            khiA[4 * s + i] = min(K_BINS - 1, (int)floorf(right));
        }
    }

    // ---- merge the 8 ascending intervals into <=8 runs (scalars only) ----
    int RS0 = kloA[0], RE0 = khiA[0];
    int RS1 = 0, RE1 = -1, RS2 = 0, RE2 = -1, RS3 = 0, RE3 = -1;
    int RS4 = 0, RE4 = -1, RS5 = 0, RE5 = -1, RS6 = 0, RE6 = -1, RS7 = 0, RE7 = -1;
    int nr = 1;
#pragma unroll
    for (int fi = 1; fi < 8; ++fi) {
        const int s = kloA[fi], e = khiA[fi];
        const int le = sel8(nr - 1, RE0, RE1, RE2, RE3, RE4, RE5, RE6, RE7);
        if (s <= le + 1) {
            const int ne = max(le, e);
            switch (nr - 1) {
                case 0: RE0 = ne; break; case 1: RE1 = ne; break;
                case 2: RE2 = ne; break; case 3: RE3 = ne; break;
                case 4: RE4 = ne; break; case 5: RE5 = ne; break;
                case 6: RE6 = ne; break; default: RE7 = ne; break;
            }
        } else {
            switch (nr) {
                case 1: RS1 = s; RE1 = e; break; case 2: RS2 = s; RE2 = e; break;
                case 3: RS3 = s; RE3 = e; break; case 4: RS4 = s; RE4 = e; break;
                case 5: RS5 = s; RE5 = e; break; case 6: RS6 = s; RE6 = e; break;
                default: RS7 = s; RE7 = e; break;
            }
            ++nr;
        }
    }

    float4 acc[2][4][2];
#pragma unroll
    for (int s = 0; s < 2; ++s)
#pragma unroll
        for (int i = 0; i < 4; ++i) {
            acc[s][i][0] = make_float4(0.f, 0.f, 0.f, 0.f);
            acc[s][i][1] = make_float4(0.f, 0.f, 0.f, 0.f);
        }

    // ---- two cursors over the run list ----
    int rI = 0, kI = RS0, reI = RE0;   // issue
    int rU = 0, kU = RS0, reU = RE0;   // use
#define ADV(rX, kX, reX)                                                    \
    { if (kX + 1 <= reX) { ++kX; }                                          \
      else { ++rX;                                                          \
             if (rX < nr) {                                                 \
                 kX  = sel8(rX, RS0, RS1, RS2, RS3, RS4, RS5, RS6, RS7);    \
                 reX = sel8(rX, RE0, RE1, RE2, RE3, RE4, RE5, RE6, RE7);    \
             } else kX = -1; } }

#define STAGE(sl, k)                                                        \
    { const float4* rp_ = base4 + (size_t)(k) * ROWQ;                       \
      float4* dst_ = slab + (sl) * SLOTF4;                                  \
      load_lds16(rp_ + lane, dst_);                                         \
      load_lds16(rp_ + li1, dst_ + 64); }

    int inflight = 0;
    if (kI >= 0) { STAGE(0, kI); ADV(rI, kI, reI); ++inflight; }
    if (kI >= 0) { STAGE(1, kI); ADV(rI, kI, reI); ++inflight; }
    if (kI >= 0) { STAGE(2, kI); ADV(rI, kI, reI); ++inflight; }

    int slot = 0;
    while (kU >= 0) {
        if (kI >= 0) { STAGE((slot + 3) & 3, kI); ADV(rI, kI, reI); ++inflight; }
        const int allow = inflight - 1;        // rows allowed to stay in flight
        if (allow >= 3)      asm volatile("s_waitcnt vmcnt(6)" ::: "memory");
        else if (allow == 2) asm volatile("s_waitcnt vmcnt(4)" ::: "memory");
        else if (allow == 1) asm volatile("s_waitcnt vmcnt(2)" ::: "memory");
        else                 asm volatile("s_waitcnt vmcnt(0)" ::: "memory");

        const float4* sp = slab + slot * SLOTF4;
        float4 v0 = sp[lane];
        float4 v1 = sp[64 + lane];
        float fk = (float)kU;
#pragma unroll
        for (int s = 0; s < 2; ++s)
#pragma unroll
            for (int i = 0; i < 4; ++i) {
                float wg = fmaxf(0.0f,
                                 fminf(fmaf(fk, ic[s][i],  mA[s][i]),
                                       fmaf(fk, mir[s][i], Bf[s][i])));
                acc[s][i][0].x = fmaf(wg, v0.x, acc[s][i][0].x);
                acc[s][i][0].y = fmaf(wg, v0.y, acc[s][i][0].y);
                acc[s][i][0].z = fmaf(wg, v0.z, acc[s][i][0].z);
                acc[s][i][0].w = fmaf(wg, v0.w, acc[s][i][0].w);
                acc[s][i][1].x = fmaf(wg, v1.x, acc[s][i][1].x);
                acc[s][i][1].y = fmaf(wg, v1.y, acc[s][i][1].y);
                acc[s][i][1].z = fmaf(wg, v1.z, acc[s][i][1].z);
                acc[s][i][1].w = fmaf(wg, v1.w, acc[s][i][1].w);
            }
        --inflight;
        slot = (slot + 1) & 3;
        ADV(rU, kU, reU);
    }
#undef STAGE
#undef ADV

    // ---- Epilogue: col-major LDS transpose (aliases the ring, post-barrier).
    float (*tile2)[516] = (float (*)[516])smem4;   // 16 x 516 floats = 33 KB
#pragma unroll
    for (int i = 0; i < 4; ++i) {
        __syncthreads();               // all waves done with ring / prev tile
        {
            const int col0 = 4 * p + jj;        // task0 band col
            const int col1 = 4 * p + (3 - jj);  // task1 band col
            *reinterpret_cast<float4*>(&tile2[col0][4 * lane]) = acc[0][i][0];
            *reinterpret_cast<float4*>(&tile2[col1][4 * lane]) = acc[1][i][0];
            if (ok1) {
                *reinterpret_cast<float4*>(&tile2[col0][256 + 4 * lane]) = acc[0][i][1];
                *reinterpret_cast<float4*>(&tile2[col1][256 + 4 * lane]) = acc[1][i][1];
            }
        }
        __syncthreads();
        const int b2 = 4 * B + i;
        const int c4 = tid & 3;
#pragma unroll
        for (int rr = 0; rr < 4; ++rr) {
            int tl = 128 * rr + (tid >> 2);
            if (tl < TQ) {
                float4 v = make_float4(tile2[4 * c4 + 0][tl], tile2[4 * c4 + 1][tl],
                                       tile2[4 * c4 + 2][tl], tile2[4 * c4 + 3][tl]);
                *reinterpret_cast<float4*>(
                    out + ((size_t)b2 * T_LEN + t0 + tl) * NF + 16 * q + 4 * c4) = v;
            }
        }
    }
}

extern "C" void kernel_launch(void* const* d_in, const int* in_sizes, int n_in,
                              void* d_out, int out_size, void* d_ws, size_t ws_size,
                              hipStream_t stream) {
    const float* spec = (const float*)d_in[0];   // (32, 1025, 2000) f32
    const float* cf   = (const float*)d_in[1];   // (128,)
    const float* bwv  = (const float*)d_in[2];   // (128,)
    const float* fs   = (const float*)d_in[3];   // (128, 2)
    float* out = (float*)d_out;                  // (32, 2000, 128) f32

    fb_fused<<<dim3(8, 8, 4), 512, 0, stream>>>(spec, cf, bwv, fs, out);
}

// Round 14
// 62.069 us; speedup vs baseline: 3.1129x; 1.3215x over previous
//
#include <hip/hip_runtime.h>

#define K_BINS 1025
#define T_LEN  2000
#define NF     128
#define TQ     500    // t per block (2000 = 4*500, no tail)
#define ROWQ   500    // float4 per full k-row
#define SLICE  524    // floats per i-slice; LDS row = 4*SLICE = 2096 (%32 = 16 -> 2-way reads)

__device__ __forceinline__ float softplusf(float x) {
    // matches jax.nn.softplus = max(x,0) + log1p(exp(-|x|))
    return fmaxf(x, 0.0f) + log1pf(expf(-fabsf(x)));
}

// out[b2][t][4*bp + w] = sum_k w_f(k) * spec[bp][k][t],  f = b2 + 32*w
// Block = (bp-quad q, b2-quad B, t-quarter th). 1024 thr = 16 waves (w,p).
// Wave (w,p): filters f = 4B+32w+i for bp = 4q+p, walking its merged-run
// union in STATIC CHUNKS OF 4 ROWS: 8 independent global loads issued at the
// top of each body, consumed by 4 static ROW blocks below. The compiler's
// own waitcnt pass then emits counted vmcnt(6/4/2/0) -> 4 rows in flight
// (R6-R9: while-loop copy chains serialized at 1 row = ~1.3 us/row;
// R13: LDS-DMA ring was drained to vmcnt(0) by the compiler's alias wait).
// Live loads bounded at 8 float4 -> no R11/R12 spills. Pad rows past a run
// end are masked by wave-uniform k<=ke (kills run double-count + R10 bug).
// 134 KB LDS forces 1 block/CU -> compiler must budget 128 VGPR, not 64.
// Epilogue: single-sync col-major tile [16][4*SLICE], float4 ds_writes,
// full 64 B line float4 stores.
__global__ __launch_bounds__(1024) void fb_fused(
        const float* __restrict__ spec,
        const float* __restrict__ cf,
        const float* __restrict__ bwv,
        const float* __restrict__ fs,
        float*       __restrict__ out) {
    __shared__ float tile2[16][4 * SLICE];   // 134,144 B

    const int q    = blockIdx.x;   // bp-quad 0..7 (id%8 -> XCD q)
    const int B    = blockIdx.y;   // b2-quad 0..7
    const int th   = blockIdx.z;   // t-quarter 0..3
    const int tid  = threadIdx.x;
    const int lane = tid & 63;
    const int wid  = tid >> 6;     // 0..15
    const int w    = wid >> 2;     // filter band 0..3
    const int p    = wid & 3;      // bp-local 0..3
    const int bp   = 4 * q + p;
    const int t0   = TQ * th;
    const bool ok1 = lane < (TQ / 4 - 64);       // second float4 live (lane<61)
    const int  li1 = min(64 + lane, TQ / 4 - 1); // clamped: always in-bounds

    const float4* base4 =
        (const float4*)(spec + (size_t)bp * (K_BINS * (size_t)T_LEN) + t0);

    // ---- params for the 4 adjacent filters of band w, quad B ----
    float ic[4], mir[4], mA[4], Bfc[4];
    int   klo4[4], khi4[4];                 // static-indexed only
#pragma unroll
    for (int i = 0; i < 4; ++i) {
        const int f = 4 * B + 32 * w + i;
        float c  = cf[f];
        float bw = softplusf(bwv[f]) + 0.001f;
        float s0 = softplusf(fs[2 * f])     + 0.1f;
        float s1 = softplusf(fs[2 * f + 1]) + 0.1f;
        float left  = c - bw * s0;
        float right = c + bw * s1;
        float icv = 1.0f / (c - left + 1e-8f);
        float irv = 1.0f / (right - c + 1e-8f);
        ic[i]  = icv;
        mir[i] = -irv;
        mA[i]  = -left * icv;           // rise = fk*ic + mA
        Bfc[i] = fmaf(c, irv, 1.0f);    // fall = fk*mir + Bfc
        klo4[i] = max(0, (int)ceilf(left));
        khi4[i] = min(K_BINS - 1, (int)floorf(right));
    }

    // ---- merge the 4 ascending intervals into <=4 runs (named scalars) ----
    int RS0 = klo4[0], RE0 = khi4[0];
    int RS1 = 0, RE1 = -1, RS2 = 0, RE2 = -1, RS3 = 0, RE3 = -1;
    int nr = 1;
#pragma unroll
    for (int i = 1; i < 4; ++i) {
        const int s = klo4[i], e = khi4[i];
        const int le = (nr == 1) ? RE0 : (nr == 2) ? RE1 : RE2;
        if (s <= le + 1) {
            const int ne = max(le, e);
            if (nr == 1) RE0 = ne; else if (nr == 2) RE1 = ne; else RE2 = ne;
        } else {
            if (nr == 1)      { RS1 = s; RE1 = e; }
            else if (nr == 2) { RS2 = s; RE2 = e; }
            else              { RS3 = s; RE3 = e; }
            ++nr;
        }
    }

    float4 acc[4][2];              // [filter i][t-half]
#pragma unroll
    for (int i = 0; i < 4; ++i) {
        acc[i][0] = make_float4(0.f, 0.f, 0.f, 0.f);
        acc[i][1] = make_float4(0.f, 0.f, 0.f, 0.f);
    }

#define ROWSTEP(KK, VA, VB)                                                 \
    { const int   k_  = (KK);                                               \
      const float fk_ = (float)k_;                                          \
      const bool  lv_ = (k_ <= ke);     /* ke<=1024: masks pad + top edge */ \
      _Pragma("unroll")                                                     \
      for (int i = 0; i < 4; ++i) {                                         \
          float wg = fmaxf(0.0f, fminf(fmaf(fk_, ic[i],  mA[i]),            \
                                       fmaf(fk_, mir[i], Bfc[i])));         \
          wg = lv_ ? wg : 0.0f;                                             \
          acc[i][0].x = fmaf(wg, VA.x, acc[i][0].x);                        \
          acc[i][0].y = fmaf(wg, VA.y, acc[i][0].y);                        \
          acc[i][0].z = fmaf(wg, VA.z, acc[i][0].z);                        \
          acc[i][0].w = fmaf(wg, VA.w, acc[i][0].w);                        \
          acc[i][1].x = fmaf(wg, VB.x, acc[i][1].x);                        \
          acc[i][1].y = fmaf(wg, VB.y, acc[i][1].y);                        \
          acc[i][1].z = fmaf(wg, VB.z, acc[i][1].z);                        \
          acc[i][1].w = fmaf(wg, VB.w, acc[i][1].w);                        \
      } }

#pragma unroll
    for (int r = 0; r < 4; ++r) {
        int ks, ke;
        if      (r == 0) { ks = RS0; ke = RE0; }
        else if (r == 1) { ks = RS1; ke = RE1; }
        else if (r == 2) { ks = RS2; ke = RE2; }
        else             { ks = RS3; ke = RE3; }
        for (int k0 = ks; k0 <= ke; k0 += 4) {      // 4-row static body
            const float4* rp0 = base4 + (size_t)min(k0,     K_BINS - 1) * ROWQ;
            const float4* rp1 = base4 + (size_t)min(k0 + 1, K_BINS - 1) * ROWQ;
            const float4* rp2 = base4 + (size_t)min(k0 + 2, K_BINS - 1) * ROWQ;
            const float4* rp3 = base4 + (size_t)min(k0 + 3, K_BINS - 1) * ROWQ;
            float4 a0 = rp0[lane], b0 = rp0[li1];   // 8 independent loads
            float4 a1 = rp1[lane], b1 = rp1[li1];   // -> compiler emits counted
            float4 a2 = rp2[lane], b2 = rp2[li1];   //    vmcnt(6/4/2/0)
            float4 a3 = rp3[lane], b3 = rp3[li1];
            ROWSTEP(k0 + 0, a0, b0);
            ROWSTEP(k0 + 1, a1, b1);
            ROWSTEP(k0 + 2, a2, b2);
            ROWSTEP(k0 + 3, a3, b3);
        }
    }
#undef ROWSTEP

    // ---- Epilogue: single-sync col-major transpose, full 64 B line stores.
    {
        const int col = 4 * p + w;          // f2 - 16q (distinct per wave)
#pragma unroll
        for (int i = 0; i < 4; ++i) {
            *reinterpret_cast<float4*>(&tile2[col][i * SLICE + 4 * lane]) = acc[i][0];
            if (ok1)
                *reinterpret_cast<float4*>(&tile2[col][i * SLICE + 256 + 4 * lane]) = acc[i][1];
        }
    }
    __syncthreads();
    {
        const int c4 = tid & 3;
#pragma unroll
        for (int i = 0; i < 4; ++i) {
            const int b2 = 4 * B + i;
#pragma unroll
            for (int rr = 0; rr < 2; ++rr) {
                int tl = 256 * rr + (tid >> 2);
                if (tl < TQ) {
                    float4 v = make_float4(tile2[4 * c4 + 0][i * SLICE + tl],
                                           tile2[4 * c4 + 1][i * SLICE + tl],
                                           tile2[4 * c4 + 2][i * SLICE + tl],
                                           tile2[4 * c4 + 3][i * SLICE + tl]);
                    *reinterpret_cast<float4*>(
                        out + ((size_t)b2 * T_LEN + t0 + tl) * NF + 16 * q + 4 * c4) = v;
                }
            }
        }
    }
}

extern "C" void kernel_launch(void* const* d_in, const int* in_sizes, int n_in,
                              void* d_out, int out_size, void* d_ws, size_t ws_size,
                              hipStream_t stream) {
    const float* spec = (const float*)d_in[0];   // (32, 1025, 2000) f32
    const float* cf   = (const float*)d_in[1];   // (128,)
    const float* bwv  = (const float*)d_in[2];   // (128,)
    const float* fs   = (const float*)d_in[3];   // (128, 2)
    float* out = (float*)d_out;                  // (32, 2000, 128) f32

    fb_fused<<<dim3(8, 8, 4), 1024, 0, stream>>>(spec, cf, bwv, fs, out);
}